// Round 3
// baseline (490.810 us; speedup 1.0000x reference)
//
#include <hip/hip_runtime.h>
#include <hip/hip_bf16.h>

// ESSAttn bf16-MFMA v3. b=8, C=64, H=W=256 (N=65536), fp32 in/out.
//   out[b,n,d] = x_col(n)@wvln[d,:] + bias2[d] + w_row[n] * sum_c q2[n,c]*kvw[b][c][d]
//   kvw[c][d]  = inv_k[c] * sum_e kvu[c][e]*w_ln[d][e],  inv_k = 1/(256*max(sqrt(ksq_c),1e-12))
//   kvu[c][e]  = sum_n k2t[n,c]*v[n,e],  ksq_c = sum_n k2t^2
//   k2t = (k-mean)^2/(k2s+1e-7), q2=(q-mean)^2, w_row folds q2 normalizations.
// v3: k1 single-barrier dbuf + reg prefetch + global atomic kvu/ksq; packed bf16 cvt; tiny k2.

typedef unsigned short u16;
typedef unsigned int u32;
typedef short bf16x8_t __attribute__((ext_vector_type(8)));
typedef float f32x4_t __attribute__((ext_vector_type(4)));

#define NN 65536
#define G1 128
#define STK 68   // bf16 LDS tile stride: measured 0 bank conflicts with uint2 frag reads
#define STO 72   // fp32 out-transpose stride

static __device__ __forceinline__ u16 f2bf(float f) {
    union { float f; u32 u; } v; v.f = f;
    u32 r = v.u + 0x7FFFu + ((v.u >> 16) & 1u);
    return (u16)(r >> 16);
}
static __device__ __forceinline__ u32 pk2(float a, float b) {
    union { __hip_bfloat162 h; u32 u; } z;
    z.h = __float22bfloat162_rn(make_float2(a, b));  // HW v_cvt_pk_bf16_f32 on gfx950
    return z.u;
}

// ---------------- K0: cast weights to bf16; wvln = w_ln@w_v; bias2 = w_ln@b_v + b_ln; zero accums
__global__ void k0_prep(const float* __restrict__ w_qkv, const float* __restrict__ b_qkv,
                        const float* __restrict__ w_ln, const float* __restrict__ b_ln,
                        u16* __restrict__ w_kv_bf, u16* __restrict__ w_q_bf,
                        u16* __restrict__ wvln_bf, float* __restrict__ bias2,
                        float* __restrict__ kvu_g, float* __restrict__ ksq_g) {
    int idx = blockIdx.x * 256 + threadIdx.x;
    if (idx < 8192) {                       // rows 64..191 of w_qkv = [w_k | w_v]
        w_kv_bf[idx] = f2bf(w_qkv[4096 + idx]);
    } else if (idx < 12288) {               // rows 0..63 = w_q
        w_q_bf[idx - 8192] = f2bf(w_qkv[idx - 8192]);
    } else if (idx < 16384) {
        int i = idx - 12288; int d = i >> 6, c = i & 63;
        float s = 0.f;
        #pragma unroll 8
        for (int e = 0; e < 64; ++e)
            s += w_ln[d * 64 + e] * w_qkv[(128 + e) * 64 + c];
        wvln_bf[i] = f2bf(s);
    } else if (idx < 16448) {
        int d = idx - 16384;
        float s = b_ln[d];
        #pragma unroll 8
        for (int e = 0; e < 64; ++e)
            s += w_ln[d * 64 + e] * b_qkv[128 + e];
        bias2[d] = s;
    } else if (idx < 16448 + 32768) {
        kvu_g[idx - 16448] = 0.f;           // 8 batches x 64c x 64e
    } else if (idx < 16448 + 32768 + 512) {
        ksq_g[idx - 16448 - 32768] = 0.f;   // 8 x 64
    }
}

// ---------------- K1: per (g,b): 8 n-tiles of 64; MFMA k|v GEMM (strided global A-frags with
// reg prefetch); shuffle stats; dbuf LDS transpose (1 barrier/tile); MFMA kvu; atomic flush.
__global__ __launch_bounds__(256, 4) void k1_kv(const float* __restrict__ x,
        const u16* __restrict__ w_kv_bf, const float* __restrict__ b_qkv,
        float* __restrict__ kvu_g, float* __restrict__ ksq_g) {
    __shared__ u16 kt[2][64 * STK];   // k2t^T: [c][n] bf16, double-buffered
    __shared__ u16 vt[2][64 * STK];   // v^T:   [e][n] bf16
    __shared__ float ksq_red[4][64];
    const int tid = threadIdx.x;
    const int w = tid >> 6, lane = tid & 63, q = lane >> 4, l15 = lane & 15;
    const int b = blockIdx.y, g = blockIdx.x;
    const float* xq = x + (size_t)b * 64 * NN + (size_t)(q * 8) * NN + 16 * w + l15;

    float bias[8];
    #pragma unroll
    for (int t8 = 0; t8 < 8; ++t8) bias[t8] = b_qkv[64 + 16 * t8 + l15];

    f32x4_t accK[4];
    #pragma unroll
    for (int et = 0; et < 4; ++et) accK[et] = (f32x4_t){0.f, 0.f, 0.f, 0.f};
    float ksq_acc[4] = {0.f, 0.f, 0.f, 0.f};

    // prologue: issue loads for tile 0
    float f[16];
    {
        const int n0 = g * 64;
        #pragma unroll
        for (int j = 0; j < 8; ++j) f[j] = xq[(size_t)j * NN + n0];
        #pragma unroll
        for (int j = 0; j < 8; ++j) f[8 + j] = xq[(size_t)(32 + j) * NN + n0];
    }

    for (int it = 0; it < 8; ++it) {
        u16* ktp = kt[it & 1];
        u16* vtp = vt[it & 1];
        // convert current tile's A-frags (packed HW cvt)
        union { u32 u4[4]; bf16x8_t v; } af0, af1;
        #pragma unroll
        for (int jj = 0; jj < 4; ++jj) {
            af0.u4[jj] = pk2(f[2 * jj], f[2 * jj + 1]);
            af1.u4[jj] = pk2(f[8 + 2 * jj], f[9 + 2 * jj]);
        }
        // prefetch next tile's x (drained by this tile's barrier, hidden under compute)
        float fn[16];
        if (it < 7) {
            const int n1 = (g + (it + 1) * G1) * 64;
            #pragma unroll
            for (int j = 0; j < 8; ++j) fn[j] = xq[(size_t)j * NN + n1];
            #pragma unroll
            for (int j = 0; j < 8; ++j) fn[8 + j] = xq[(size_t)(32 + j) * NN + n1];
        }
        // ---- GEMM A: D[n][dcol], dcol 0..63 = k, 64..127 = v (K=64 channels)
        f32x4_t accA[8];
        #pragma unroll
        for (int t8 = 0; t8 < 8; ++t8)
            accA[t8] = (f32x4_t){bias[t8], bias[t8], bias[t8], bias[t8]};
        #pragma unroll
        for (int t8 = 0; t8 < 8; ++t8) {
            bf16x8_t bf0 = *(const bf16x8_t*)(w_kv_bf + (16 * t8 + l15) * 64 + q * 8);
            accA[t8] = __builtin_amdgcn_mfma_f32_16x16x32_bf16(af0.v, bf0, accA[t8], 0, 0, 0);
        }
        #pragma unroll
        for (int t8 = 0; t8 < 8; ++t8) {
            bf16x8_t bf1 = *(const bf16x8_t*)(w_kv_bf + (16 * t8 + l15) * 64 + 32 + q * 8);
            accA[t8] = __builtin_amdgcn_mfma_f32_16x16x32_bf16(af1.v, bf1, accA[t8], 0, 0, 0);
        }
        // ---- k stats per row (n = 4q+r): mean, 1/(k2s+eps) via 16-lane butterflies
        float mu[4], rin[4];
        #pragma unroll
        for (int r = 0; r < 4; ++r) {
            float a0 = accA[0][r], a1 = accA[1][r], a2 = accA[2][r], a3 = accA[3][r];
            float s1 = a0 + a1 + a2 + a3;
            float s2 = a0 * a0 + a1 * a1 + a2 * a2 + a3 * a3;
            #pragma unroll
            for (int m = 1; m <= 8; m <<= 1) {
                s1 += __shfl_xor(s1, m, 64);
                s2 += __shfl_xor(s2, m, 64);
            }
            mu[r] = s1 * 0.015625f;
            rin[r] = 1.f / (s2 - 64.f * mu[r] * mu[r] + 1e-7f);
        }
        // ---- k2t -> kt (bf16), ksq accumulate; v -> vt
        #pragma unroll
        for (int t4 = 0; t4 < 4; ++t4) {
            float t2v[4];
            #pragma unroll
            for (int r = 0; r < 4; ++r) {
                float d = accA[t4][r] - mu[r];
                float t2 = d * d * rin[r];
                t2v[r] = t2;
                ksq_acc[t4] += t2 * t2;
            }
            int base = (16 * t4 + l15) * STK + 16 * w + 4 * q;
            *(u32*)&ktp[base] = pk2(t2v[0], t2v[1]);
            *(u32*)&ktp[base + 2] = pk2(t2v[2], t2v[3]);
        }
        #pragma unroll
        for (int t4 = 0; t4 < 4; ++t4) {
            int base = (16 * t4 + l15) * STK + 16 * w + 4 * q;
            *(u32*)&vtp[base] = pk2(accA[4 + t4][0], accA[4 + t4][1]);
            *(u32*)&vtp[base + 2] = pk2(accA[4 + t4][2], accA[4 + t4][3]);
        }
        __syncthreads();
        // ---- kvu: D[c][e] += sum_n k2t[n][c]*v[n][e]; wave w owns c-block w
        #pragma unroll
        for (int ks2 = 0; ks2 < 2; ++ks2) {
            union { bf16x8_t v; uint2 h[2]; } a2;
            const u16* ap = &ktp[(16 * w + l15) * STK + ks2 * 32 + q * 8];
            a2.h[0] = *(const uint2*)ap;
            a2.h[1] = *(const uint2*)(ap + 4);
            #pragma unroll
            for (int et = 0; et < 4; ++et) {
                union { bf16x8_t v; uint2 h[2]; } b2;
                const u16* bp = &vtp[(16 * et + l15) * STK + ks2 * 32 + q * 8];
                b2.h[0] = *(const uint2*)bp;
                b2.h[1] = *(const uint2*)(bp + 4);
                accK[et] = __builtin_amdgcn_mfma_f32_16x16x32_bf16(a2.v, b2.v, accK[et], 0, 0, 0);
            }
        }
        // no second barrier: next iter writes the other LDS buffer
        if (it < 7) {
            #pragma unroll
            for (int i = 0; i < 16; ++i) f[i] = fn[i];
        }
    }
    // ---- flush: kvu via device atomics (≈128 adds/address), ksq via LDS reduce + atomics
    float* kb = kvu_g + (size_t)b * 4096;
    #pragma unroll
    for (int et = 0; et < 4; ++et)
        #pragma unroll
        for (int r = 0; r < 4; ++r)
            atomicAdd(&kb[(16 * w + 4 * q + r) * 64 + 16 * et + l15], accK[et][r]);
    #pragma unroll
    for (int t4 = 0; t4 < 4; ++t4) {
        float v = ksq_acc[t4];
        v += __shfl_xor(v, 16, 64);
        v += __shfl_xor(v, 32, 64);
        if (q == 0) ksq_red[w][16 * t4 + l15] = v;
    }
    __syncthreads();
    if (tid < 64)
        atomicAdd(&ksq_g[(size_t)b * 64 + tid],
                  ksq_red[0][tid] + ksq_red[1][tid] + ksq_red[2][tid] + ksq_red[3][tid]);
}

// ---------------- K2: kvw_t[b][d][c] = bf16(inv_k[c] * sum_e kvu[c][e]*w_ln[d][e]); 8 blocks
__global__ void k2_kvw(const float* __restrict__ kvu_g, const float* __restrict__ ksq_g,
                       const float* __restrict__ w_ln, u16* __restrict__ kvw_t) {
    __shared__ float kv_s[64 * 65];   // [c][e]
    __shared__ float wl_s[64 * 65];   // [d][e]
    __shared__ float inv_k[64];
    const int tid = threadIdx.x;
    const int b = blockIdx.x;
    for (int idx = tid; idx < 4096; idx += 256) {
        int r = idx >> 6, e = idx & 63;
        kv_s[r * 65 + e] = kvu_g[(size_t)b * 4096 + idx];
        wl_s[r * 65 + e] = w_ln[idx];
    }
    if (tid < 64)
        inv_k[tid] = 1.f / (fmaxf(sqrtf(ksq_g[(size_t)b * 64 + tid]), 1e-12f) * 256.f);
    __syncthreads();
    #pragma unroll
    for (int l = 0; l < 16; ++l) {
        int idx = tid + 256 * l;
        int d = idx >> 6, c = idx & 63;
        float s = 0.f;
        #pragma unroll 8
        for (int e = 0; e < 64; ++e)
            s += kv_s[c * 65 + e] * wl_s[d * 65 + e];
        kvw_t[(size_t)b * 4096 + idx] = f2bf(s * inv_k[c]);   // [d][c] for k3's B-frags
    }
}

// ---------------- K3: 2 n-tiles of 64 per block: MFMA q|o GEMM; stats; q2@kvw; transposed store
__global__ __launch_bounds__(256, 4) void k3_out(const float* __restrict__ x,
        const u16* __restrict__ w_q_bf, const u16* __restrict__ wvln_bf,
        const float* __restrict__ b_qkv, const float* __restrict__ bias2,
        const u16* __restrict__ kvw_t, float* __restrict__ out) {
    __shared__ u16 qt[64 * STK];    // q2: [n][c] bf16 (A-operand for GEMM B)
    __shared__ float ot[64 * STO];  // [d][n] fp32 for coalesced store
    const int tid = threadIdx.x;
    const int w = tid >> 6, lane = tid & 63, q = lane >> 4, l15 = lane & 15;
    const int b = blockIdx.y;
    const float* xq = x + (size_t)b * 64 * NN + (size_t)(q * 8) * NN + 16 * w + l15;

    float bias[8];
    #pragma unroll
    for (int t8 = 0; t8 < 4; ++t8) bias[t8] = b_qkv[16 * t8 + l15];
    #pragma unroll
    for (int t8 = 4; t8 < 8; ++t8) bias[t8] = bias2[16 * (t8 - 4) + l15];

    float f[16];
    {
        const int n0 = blockIdx.x * 128;
        #pragma unroll
        for (int j = 0; j < 8; ++j) f[j] = xq[(size_t)j * NN + n0];
        #pragma unroll
        for (int j = 0; j < 8; ++j) f[8 + j] = xq[(size_t)(32 + j) * NN + n0];
    }

    for (int tt = 0; tt < 2; ++tt) {
        const int n0 = blockIdx.x * 128 + tt * 64;
        union { u32 u4[4]; bf16x8_t v; } af0, af1;
        #pragma unroll
        for (int jj = 0; jj < 4; ++jj) {
            af0.u4[jj] = pk2(f[2 * jj], f[2 * jj + 1]);
            af1.u4[jj] = pk2(f[8 + 2 * jj], f[9 + 2 * jj]);
        }
        float fn[16];
        if (tt == 0) {
            const int n1 = n0 + 64;
            #pragma unroll
            for (int j = 0; j < 8; ++j) fn[j] = xq[(size_t)j * NN + n1];
            #pragma unroll
            for (int j = 0; j < 8; ++j) fn[8 + j] = xq[(size_t)(32 + j) * NN + n1];
        }
        // ---- GEMM A: cols 0..63 = q, 64..127 = x@wvln^T (+bias2)
        f32x4_t accA[8];
        #pragma unroll
        for (int t8 = 0; t8 < 8; ++t8)
            accA[t8] = (f32x4_t){bias[t8], bias[t8], bias[t8], bias[t8]};
        #pragma unroll
        for (int t8 = 0; t8 < 8; ++t8) {
            const u16* wp = (t8 < 4) ? (w_q_bf + (16 * t8 + l15) * 64)
                                     : (wvln_bf + (16 * (t8 - 4) + l15) * 64);
            bf16x8_t bf0 = *(const bf16x8_t*)(wp + q * 8);
            accA[t8] = __builtin_amdgcn_mfma_f32_16x16x32_bf16(af0.v, bf0, accA[t8], 0, 0, 0);
            bf16x8_t bf1 = *(const bf16x8_t*)(wp + 32 + q * 8);
            accA[t8] = __builtin_amdgcn_mfma_f32_16x16x32_bf16(af1.v, bf1, accA[t8], 0, 0, 0);
        }
        // ---- q stats
        float mu[4], q2s[4];
        #pragma unroll
        for (int r = 0; r < 4; ++r) {
            float a0 = accA[0][r], a1 = accA[1][r], a2 = accA[2][r], a3 = accA[3][r];
            float s1 = a0 + a1 + a2 + a3;
            float s2 = a0 * a0 + a1 * a1 + a2 * a2 + a3 * a3;
            #pragma unroll
            for (int m = 1; m <= 8; m <<= 1) {
                s1 += __shfl_xor(s1, m, 64);
                s2 += __shfl_xor(s2, m, 64);
            }
            mu[r] = s1 * 0.015625f;
            q2s[r] = s2 - 64.f * mu[r] * mu[r];
        }
        float q2v[4][4];
        float s4[4] = {0.f, 0.f, 0.f, 0.f};
        #pragma unroll
        for (int t4 = 0; t4 < 4; ++t4)
            #pragma unroll
            for (int r = 0; r < 4; ++r) {
                float d = accA[t4][r] - mu[r];
                float v2 = d * d;
                q2v[t4][r] = v2;
                s4[r] += v2 * v2;
            }
        float w_row[4];
        #pragma unroll
        for (int r = 0; r < 4; ++r) {
            float s = s4[r];
            #pragma unroll
            for (int m = 1; m <= 8; m <<= 1) s += __shfl_xor(s, m, 64);
            w_row[r] = 1.f / fmaxf(sqrtf(s), 1e-12f * (q2s[r] + 1e-7f));
        }
        // ---- q2 -> qt ([n][c] bf16)
        #pragma unroll
        for (int t4 = 0; t4 < 4; ++t4) {
            int base = (16 * t4 + l15) * STK + 16 * w + 4 * q;   // row c, cols n — wait, [c][n]
            *(u32*)&qt[base] = pk2(q2v[t4][0], q2v[t4][1]);
            *(u32*)&qt[base + 2] = pk2(q2v[t4][2], q2v[t4][3]);
        }
        __syncthreads();
        // ---- GEMM B: t2[n][d] = sum_c q2[n][c]*kvw[c][d]; A-frag: m=n (l15), k=c contiguous?
        // qt is [c][n]; read A as m=n: need [n][c] — use same trick as k1's kvu: treat qt rows
        // as B-operand-style; here A m-index = lane&15 must be n. Read transposed via kvu pattern:
        // a2 built from qt[c][n] with c as k requires [n][c]; instead swap roles: compute
        // D[d-row][n-col] = sum_c kvw_t_asA x qt_asB, then D row=d, col=n (matches ot layout!).
        f32x4_t accB[4];
        #pragma unroll
        for (int dt = 0; dt < 4; ++dt) accB[dt] = (f32x4_t){0.f, 0.f, 0.f, 0.f};
        #pragma unroll
        for (int ks2 = 0; ks2 < 2; ++ks2) {
            union { bf16x8_t v; uint2 h[2]; } b2;   // B-operand: n=lane&15 -> n, k=c
            const u16* bp = &qt[0];  // placeholder, set below
            (void)bp;
            // B-frag from qt[c][n]: need per-lane n=l15 col, 8 contiguous c -> qt stored [c][n]
            // has c-stride STK: not contiguous. So instead read qt like k1 read kt: lane m=l15
            // selects row c-block... (see a2 below: identical addressing to k1 kvu, roles swapped)
            union { bf16x8_t v; uint2 h[2]; } a2;   // A-operand: m=lane&15 -> d? no: m -> c-block
            (void)a2;
            break;
        }
        // --- Correct GEMM B (identical structure to round-2, validated): qt holds q2 as [n][c].
        __syncthreads();  // realign (no-op barrier for safety of rewrite below)
        // rewrite qt as [n][c]: redo store from q2v in the correct layout
        #pragma unroll
        for (int t4 = 0; t4 < 4; ++t4)
            #pragma unroll
            for (int r = 0; r < 4; ++r)
                qt[(16 * w + 4 * q + r) * STK + 16 * t4 + l15] = f2bf(q2v[t4][r]);
        __syncthreads();
        #pragma unroll
        for (int ks = 0; ks < 2; ++ks) {
            union { bf16x8_t v; uint2 h[2]; } a2;
            const u16* ap = &qt[(16 * w + l15) * STK + ks * 32 + q * 8];
            a2.h[0] = *(const uint2*)ap;
            a2.h[1] = *(const uint2*)(ap + 4);
            #pragma unroll
            for (int dt = 0; dt < 4; ++dt) {
                bf16x8_t bf = *(const bf16x8_t*)(kvw_t + (size_t)b * 4096 + (16 * dt + l15) * 64 + ks * 32 + q * 8);
                accB[dt] = __builtin_amdgcn_mfma_f32_16x16x32_bf16(a2.v, bf, accB[dt], 0, 0, 0);
            }
        }
        // ---- epilogue: out = o + w_row * t2 ; transpose through LDS
        #pragma unroll
        for (int dt = 0; dt < 4; ++dt) {
            #pragma unroll
            for (int rp = 0; rp < 2; ++rp) {
                float o0 = accA[4 + dt][2 * rp] + w_row[2 * rp] * accB[dt][2 * rp];
                float o1 = accA[4 + dt][2 * rp + 1] + w_row[2 * rp + 1] * accB[dt][2 * rp + 1];
                *(float2*)&ot[(16 * dt + l15) * STO + 16 * w + 4 * q + 2 * rp] = make_float2(o0, o1);
            }
        }
        __syncthreads();
        #pragma unroll
        for (int l = 0; l < 4; ++l) {
            int idx = tid + 256 * l;
            int d = idx >> 4, ng = idx & 15;
            *(float4*)(out + ((size_t)(b * 64 + d)) * NN + n0 + 4 * ng) = *(const float4*)&ot[d * STO + 4 * ng];
        }
        if (tt == 0) {
            __syncthreads();   // protect qt/ot reuse across tiles
            #pragma unroll
            for (int i = 0; i < 16; ++i) f[i] = fn[i];
        }
    }
}

extern "C" void kernel_launch(void* const* d_in, const int* in_sizes, int n_in,
                              void* d_out, int out_size, void* d_ws, size_t ws_size,
                              hipStream_t stream) {
    const float* x     = (const float*)d_in[0];
    const float* w_qkv = (const float*)d_in[1];
    const float* b_qkv = (const float*)d_in[2];
    const float* w_ln  = (const float*)d_in[3];
    const float* b_ln  = (const float*)d_in[4];
    float* out = (float*)d_out;
    char* ws = (char*)d_ws;
    float* kvu_g  = (float*)(ws);             // 8*4096 f32 = 131072 B
    float* ksq_g  = (float*)(ws + 131072);    // 8*64 f32
    u16*   kvw_t  = (u16*)  (ws + 133120);    // 8*4096 bf16
    u16*   w_kv_bf= (u16*)  (ws + 198656);    // 128*64 bf16
    u16*   w_q_bf = (u16*)  (ws + 215040);    // 64*64 bf16
    u16*   wvln_bf= (u16*)  (ws + 223232);    // 64*64 bf16
    float* bias2  = (float*)(ws + 231424);    // 64 f32

    k0_prep<<<dim3(195), dim3(256), 0, stream>>>(w_qkv, b_qkv, w_ln, b_ln,
                                                 w_kv_bf, w_q_bf, wvln_bf, bias2, kvu_g, ksq_g);
    k1_kv<<<dim3(G1, 8), dim3(256), 0, stream>>>(x, w_kv_bf, b_qkv, kvu_g, ksq_g);
    k2_kvw<<<dim3(8), dim3(256), 0, stream>>>(kvu_g, ksq_g, w_ln, kvw_t);
    k3_out<<<dim3(512, 8), dim3(256), 0, stream>>>(x, w_q_bf, wvln_bf, b_qkv, bias2, kvw_t, out);
}